// Round 1
// baseline (348.393 us; speedup 1.0000x reference)
//
#include <hip/hip_runtime.h>

// VanillaNerfVoxelModel: gather from 256^3x4 f32 voxel grid + sigmoid/relu.
// pos: (N,3) f32 in [-0.6,0.6]; in-bounds iff |v|<0.5 on all axes.
// idx = trunc(v*256 + 128)  (positive range -> trunc == floor)
// out = [colors (N,3) f32 ; density (N,) f32] concatenated.

#define GRID_RES 256

__global__ __launch_bounds__(256) void nerf_voxel_kernel(
    const float* __restrict__ pos,
    const float4* __restrict__ grid,
    float* __restrict__ colors,   // N*3
    float* __restrict__ density,  // N
    int n)
{
    int i = blockIdx.x * blockDim.x + threadIdx.x;
    if (i >= n) return;

    float x = pos[3 * i + 0];
    float y = pos[3 * i + 1];
    float z = pos[3 * i + 2];

    bool cond = (fabsf(x) < 0.5f) & (fabsf(y) < 0.5f) & (fabsf(z) < 0.5f);

    float4 cad = make_float4(0.0f, 0.0f, 0.0f, 0.0f);
    if (cond) {
        // Match numpy's separate mul+add rounding (no FMA contraction).
        int ix = (int)(__fadd_rn(__fmul_rn(x, 256.0f), 128.0f));
        int iy = (int)(__fadd_rn(__fmul_rn(y, 256.0f), 128.0f));
        int iz = (int)(__fadd_rn(__fmul_rn(z, 256.0f), 128.0f));
        size_t idx = ((size_t)ix * GRID_RES + (size_t)iy) * GRID_RES + (size_t)iz;
        cad = grid[idx];
    }

    float c0 = 1.0f / (1.0f + __expf(-cad.x));
    float c1 = 1.0f / (1.0f + __expf(-cad.y));
    float c2 = 1.0f / (1.0f + __expf(-cad.z));
    float d  = fmaxf(cad.w, 0.0f);

    colors[3 * i + 0] = c0;
    colors[3 * i + 1] = c1;
    colors[3 * i + 2] = c2;
    density[i] = d;
}

extern "C" void kernel_launch(void* const* d_in, const int* in_sizes, int n_in,
                              void* d_out, int out_size, void* d_ws, size_t ws_size,
                              hipStream_t stream) {
    const float*  pos  = (const float*)d_in[0];
    const float4* grid = (const float4*)d_in[1];

    int n = in_sizes[0] / 3;                  // 2,000,000 points
    float* colors  = (float*)d_out;           // first 3*n floats
    float* density = colors + (size_t)3 * n;  // next n floats

    const int block = 256;
    const int gridsz = (n + block - 1) / block;
    hipLaunchKernelGGL(nerf_voxel_kernel, dim3(gridsz), dim3(block), 0, stream,
                       pos, grid, colors, density, n);
}